// Round 13
// baseline (255.984 us; speedup 1.0000x reference)
//
#include <hip/hip_runtime.h>
#include <cstddef>
#include <cstdint>

// Problem constants (match reference)
constexpr int CB  = 2;     // batch
constexpr int CS  = 2048;  // seq len
constexpr int CDM = 1024;  // d_model
constexpr int CH  = 16;    // heads
constexpr int CHD = 64;    // head dim
constexpr int CTPF = 128;  // tokens per frame
constexpr int CNF = 16;    // frames

typedef __attribute__((ext_vector_type(8))) short short8;
typedef __attribute__((ext_vector_type(4))) float f32x4;

__device__ inline ushort f32_bf16_rne(float x) {
  uint32_t u = __float_as_uint(x);
  u += 0x7FFFu + ((u >> 16) & 1u);
  return (ushort)(u >> 16);
}
__device__ inline float bf16_f32(ushort h) {
  return __uint_as_float(((uint32_t)h) << 16);
}
// split 8 floats into hi/lo bf16 vectors
__device__ inline void split8(const float* v, short8& H, short8& L) {
#pragma unroll
  for (int j = 0; j < 8; ++j) {
    const ushort hh = f32_bf16_rne(v[j]);
    H[j] = (short)hh;
    L[j] = (short)f32_bf16_rne(v[j] - bf16_f32(hh));
  }
}

// ---------------------------------------------------------------------------
// split_pass: fp32 -> bf16 hi/lo, memory-bound grid-stride. Runs ONCE per
// matrix so the GEMM inner loop never pays split VALU.
// ---------------------------------------------------------------------------
__global__ __launch_bounds__(256) void split_pass(
    const float* __restrict__ src, ushort* __restrict__ h,
    ushort* __restrict__ l, int n8) {
  int i = blockIdx.x * 256 + threadIdx.x;
  const int stride = gridDim.x * 256;
  for (; i < n8; i += stride) {
    float v[8];
    *(float4*)&v[0] = ((const float4*)src)[2 * i];
    *(float4*)&v[4] = ((const float4*)src)[2 * i + 1];
    short8 H, L;
    split8(v, H, L);
    *(short8*)&h[(size_t)i * 8] = H;
    *(short8*)&l[(size_t)i * 8] = L;
  }
}

// ---------------------------------------------------------------------------
// gemm_ps v2: C[M,N] = A[M,K] @ B[N,K]^T + bias[N], pre-split bf16 h/l.
// Same 3-term split MFMA math (bit-identical to R12). Staging restructured:
//  - global_load_lds width=16 (no VGPR round-trip, no staging VALU)  [m97]
//  - LDS dest LINEAR (lane-contiguous, m104 rule); swizzle applied to the
//    per-lane GLOBAL source column instead (m173/m201 stage_rc pattern)
//  - four [128][32] ushort tiles (64B rows); swz(row)=(row&6)<<2; read at
//    col ^ swz(row). Phase-level bank check (16-lane groups): row-stride
//    64B gives bank bit 4 from row&1, swz gives bits 2-3 from row bits 1-2
//    -> all 8 bank-quads covered exactly 2x per group; R12's 6.3M conflict
//    cycles (half-bank coverage per phase in the combined h|l tile) -> ~0.
// LDS 32 KB -> 5 blocks/CU.
// ---------------------------------------------------------------------------
__global__ __launch_bounds__(256) void gemm_ps(
    const ushort* __restrict__ Ah, const ushort* __restrict__ Al,
    const ushort* __restrict__ Bh, const ushort* __restrict__ Bl,
    const float* __restrict__ bias, float* __restrict__ C,
    int M, int N, int K) {
  __shared__ ushort As_h[128 * 32], As_l[128 * 32];
  __shared__ ushort Bs_h[128 * 32], Bs_l[128 * 32];
  const int tid = threadIdx.x;
  const int bm = blockIdx.y * 128;
  const int bn = blockIdx.x * 128;
  const int wid = tid >> 6;
  const int lane = tid & 63;
  const int wm = wid >> 1;
  const int wn = wid & 1;
  const int l15 = lane & 15;
  const int lk = lane >> 4;
  const int srow = tid >> 2;       // staging row (c adds 64)
  const int kq = (tid & 3) * 8;    // k-slot within 32-col half

  f32x4 acc[4][4];
#pragma unroll
  for (int i = 0; i < 4; ++i)
#pragma unroll
    for (int j = 0; j < 4; ++j) acc[i][j] = (f32x4){0.f, 0.f, 0.f, 0.f};

  for (int k0 = 0; k0 < K; k0 += 32) {
    __syncthreads();  // prev iteration's frag reads done
#pragma unroll
    for (int c = 0; c < 2; ++c) {
      const int row = srow + c * 64;
      const int kg = kq ^ ((row & 6) << 2);  // pre-swizzled global col
      const size_t ga = (size_t)(bm + row) * K + k0 + kg;
      const size_t gb = (size_t)(bn + row) * K + k0 + kg;
      const int lo = tid * 8 + c * 2048;     // linear LDS ushort offset
      __builtin_amdgcn_global_load_lds(
          (const __attribute__((address_space(1))) void*)(Ah + ga),
          (__attribute__((address_space(3))) void*)&As_h[lo], 16, 0, 0);
      __builtin_amdgcn_global_load_lds(
          (const __attribute__((address_space(1))) void*)(Al + ga),
          (__attribute__((address_space(3))) void*)&As_l[lo], 16, 0, 0);
      __builtin_amdgcn_global_load_lds(
          (const __attribute__((address_space(1))) void*)(Bh + gb),
          (__attribute__((address_space(3))) void*)&Bs_h[lo], 16, 0, 0);
      __builtin_amdgcn_global_load_lds(
          (const __attribute__((address_space(1))) void*)(Bl + gb),
          (__attribute__((address_space(3))) void*)&Bs_l[lo], 16, 0, 0);
    }
    __syncthreads();  // drains vmcnt: staged data visible

    short8 ah[4], al[4], bh[4], bl[4];
#pragma unroll
    for (int fI = 0; fI < 4; ++fI) {
      const int ar = wm * 64 + fI * 16 + l15;
      const int aoff = ar * 32 + ((lk * 8) ^ ((ar & 6) << 2));
      ah[fI] = *(const short8*)&As_h[aoff];
      al[fI] = *(const short8*)&As_l[aoff];
      const int br = wn * 64 + fI * 16 + l15;
      const int boff = br * 32 + ((lk * 8) ^ ((br & 6) << 2));
      bh[fI] = *(const short8*)&Bs_h[boff];
      bl[fI] = *(const short8*)&Bs_l[boff];
    }
#pragma unroll
    for (int mf = 0; mf < 4; ++mf)
#pragma unroll
      for (int nf = 0; nf < 4; ++nf) {
        acc[mf][nf] = __builtin_amdgcn_mfma_f32_16x16x32_bf16(
            ah[mf], bh[nf], acc[mf][nf], 0, 0, 0);
        acc[mf][nf] = __builtin_amdgcn_mfma_f32_16x16x32_bf16(
            ah[mf], bl[nf], acc[mf][nf], 0, 0, 0);
        acc[mf][nf] = __builtin_amdgcn_mfma_f32_16x16x32_bf16(
            al[mf], bh[nf], acc[mf][nf], 0, 0, 0);
      }
  }

#pragma unroll
  for (int mf = 0; mf < 4; ++mf)
#pragma unroll
    for (int nf = 0; nf < 4; ++nf) {
      const int col = bn + wn * 64 + nf * 16 + l15;
      const int row0 = bm + wm * 64 + mf * 16 + lk * 4;
      const float bc = bias[col];
#pragma unroll
      for (int i = 0; i < 4; ++i)
        C[(size_t)(row0 + i) * N + col] = acc[mf][nf][i] + bc;
    }
}

// ---------------------------------------------------------------------------
// qkv_prep v3: RMSNorm + RoPE, then PRE-SPLIT everything to bf16 h/l:
//   Qh/Ql [B,H,S,64] (pre-scaled by HD^-0.5), Kh/Kl [B,H,S,64],
//   Vth/Vtl [B,H,64,S] (transposed for PV's B-operand).
// ---------------------------------------------------------------------------
__global__ __launch_bounds__(256) void qkv_prep(
    const float* __restrict__ qkv, const float* __restrict__ q_scale,
    const float* __restrict__ k_scale,
    ushort* __restrict__ Qh, ushort* __restrict__ Ql,
    ushort* __restrict__ Kh, ushort* __restrict__ Kl,
    ushort* __restrict__ Vth, ushort* __restrict__ Vtl) {
  __shared__ float Vtile[64][68];
  const int lane = threadIdx.x & 63;
  const int w = threadIdx.x >> 6;
  const int st = blockIdx.x;   // s-tile of 64
  const int h = blockIdx.y;
  const int b = blockIdx.z;

  const float qs = q_scale[lane];
  const float ks = k_scale[lane];
  const int j = lane & 31;
  const float inv = powf(10000.0f, -(float)j * (1.0f / 32.0f));
  const float sgn = (lane < 32) ? -1.f : 1.f;

  for (int it = 0; it < 16; ++it) {
    const int sl = w * 16 + it;
    const int s = st * 64 + sl;
    const size_t row =
        ((size_t)(b * CS + s)) * (3 * CDM) + (size_t)h * CHD + lane;
    float qv = qkv[row];
    float kv = qkv[row + CDM];
    const float vv = qkv[row + 2 * CDM];

    float sq = qv * qv, sk2 = kv * kv;
#pragma unroll
    for (int off = 32; off > 0; off >>= 1) {
      sq += __shfl_xor(sq, off);
      sk2 += __shfl_xor(sk2, off);
    }
    qv *= rsqrtf(sq * (1.f / CHD) + 1e-6f) * qs;
    kv *= rsqrtf(sk2 * (1.f / CHD) + 1e-6f) * ks;

    const float ang = (float)s * inv;
    const float cs = cosf(ang);
    const float sn = sinf(ang);
    const float qp = __shfl_xor(qv, 32);
    const float kp = __shfl_xor(kv, 32);
    const float qr = fmaf(qv, cs, sgn * qp * sn) * 0.125f;  // pre-scale Q
    const float kr = fmaf(kv, cs, sgn * kp * sn);

    const size_t ob = (((size_t)(b * CH + h)) * CS + s) * CHD + lane;
    const ushort qhh = f32_bf16_rne(qr);
    Qh[ob] = qhh;
    Ql[ob] = f32_bf16_rne(qr - bf16_f32(qhh));
    const ushort khh = f32_bf16_rne(kr);
    Kh[ob] = khh;
    Kl[ob] = f32_bf16_rne(kr - bf16_f32(khh));
    Vtile[lane][sl] = vv;
  }
  __syncthreads();
  // write Vt[b,h,d, st*64 .. +63] split h/l, coalesced
  const int d = threadIdx.x >> 2;
  const int sq4 = (threadIdx.x & 3) * 16;
  const size_t vb = (((size_t)(b * CH + h)) * CHD + d) * CS + st * 64 + sq4;
#pragma unroll
  for (int j0 = 0; j0 < 16; j0 += 8) {
    float v8[8];
#pragma unroll
    for (int jj = 0; jj < 8; ++jj) v8[jj] = Vtile[d][sq4 + j0 + jj];
    short8 H, L;
    split8(v8, H, L);
    *(short8*)&Vth[vb + j0] = H;
    *(short8*)&Vtl[vb + j0] = L;
  }
}

// ---------------------------------------------------------------------------
// attn_fwd_mfma v4 (unchanged from R12): swapped QK^T, XOR-swizzled LDS,
// 3-term split, balanced frame pairing, pre-split O output.
// ---------------------------------------------------------------------------
__global__ __launch_bounds__(256, 2) void attn_fwd_mfma(
    const ushort* __restrict__ Qh, const ushort* __restrict__ Ql,
    const ushort* __restrict__ Kh, const ushort* __restrict__ Kl,
    const ushort* __restrict__ Vth, const ushort* __restrict__ Vtl,
    ushort* __restrict__ Oh, ushort* __restrict__ Ol) {
  __shared__ ushort Ks_h[64 * 64], Ks_l[64 * 64];   // K chunk [key][d]
  __shared__ ushort Vs_h[64 * 64], Vs_l[64 * 64];   // V^T chunk [d][key]
  __shared__ ushort Ps_h[128 * 64], Ps_l[128 * 64]; // P [q][key], wave-priv
  const int tid = threadIdx.x;
  const int b = blockIdx.x;
  const int h = blockIdx.y;
  const int fsel = blockIdx.z;
  const int f = (fsel < 8) ? (15 - fsel) : (fsel - 8);  // balanced pairing
  const int lane = tid & 63;
  const int wid = tid >> 6;
  const int l15 = lane & 15;
  const int lk = lane >> 4;
  const int qb = wid * 32;  // wave's queries within the frame
  const size_t hb = ((size_t)(b * CH + h)) * CS * CHD;   // Q/K [b,h,s,d]
  const size_t vtb = ((size_t)(b * CH + h)) * CHD * CS;  // Vt [b,h,d,s]

  // Q B-frags straight from pre-split global (already scaled by HD^-0.5).
  short8 qh[2][2], ql[2][2];
#pragma unroll
  for (int nf = 0; nf < 2; ++nf)
#pragma unroll
    for (int ks = 0; ks < 2; ++ks) {
      const size_t qoff = hb +
          (size_t)(f * CTPF + qb + nf * 16 + l15) * CHD + ks * 32 + lk * 8;
      qh[nf][ks] = *(const short8*)(Qh + qoff);
      ql[nf][ks] = *(const short8*)(Ql + qoff);
    }

  f32x4 accO[2][4];
#pragma unroll
  for (int mo = 0; mo < 2; ++mo)
#pragma unroll
    for (int no = 0; no < 4; ++no) accO[mo][no] = (f32x4){0.f, 0.f, 0.f, 0.f};
  float m[2] = {-1e30f, -1e30f};
  float lsum[2] = {0.f, 0.f};

  const int kf0 = (f == CNF - 1) ? 1 : 0;  // last-frame quirk
  for (int kf = kf0; kf <= f; ++kf) {
#pragma unroll 1
    for (int half = 0; half < 2; ++half) {
      const int cb = kf * CTPF + half * 64;  // chunk base key
      __syncthreads();  // prev chunk's K/V readers done
      {
        const int r = tid >> 2;            // 0..63
        const int cq = (tid & 3) * 16;     // 0,16,32,48
        const int mk = (r & 7) << 3;       // XOR swizzle (ushort units)
        // K: rows = key, cols = d
        const size_t ko = hb + (size_t)(cb + r) * CHD + cq;
        *(short8*)&Ks_h[r * 64 + (cq ^ mk)] = *(const short8*)(Kh + ko);
        *(short8*)&Ks_h[r * 64 + ((cq + 8) ^ mk)] = *(const short8*)(Kh + ko + 8);
        *(short8*)&Ks_l[r * 64 + (cq ^ mk)] = *(const short8*)(Kl + ko);
        *(short8*)&Ks_l[r * 64 + ((cq + 8) ^ mk)] = *(const short8*)(Kl + ko + 8);
        // V^T: rows = d, cols = key
        const size_t vo = vtb + (size_t)r * CS + cb + cq;
        *(short8*)&Vs_h[r * 64 + (cq ^ mk)] = *(const short8*)(Vth + vo);
        *(short8*)&Vs_h[r * 64 + ((cq + 8) ^ mk)] = *(const short8*)(Vth + vo + 8);
        *(short8*)&Vs_l[r * 64 + (cq ^ mk)] = *(const short8*)(Vtl + vo);
        *(short8*)&Vs_l[r * 64 + ((cq + 8) ^ mk)] = *(const short8*)(Vtl + vo + 8);
      }
      __syncthreads();

      // QK^T swapped: S^T[key][q]; acc frags [mf=key/16][nf=q/16]
      f32x4 sacc[4][2];
#pragma unroll
      for (int mf = 0; mf < 4; ++mf)
#pragma unroll
        for (int nf = 0; nf < 2; ++nf) sacc[mf][nf] = (f32x4){0.f, 0.f, 0.f, 0.f};
#pragma unroll
      for (int ks = 0; ks < 2; ++ks) {
        short8 kh[4], kl[4];
#pragma unroll
        for (int mf = 0; mf < 4; ++mf) {
          const int krow = mf * 16 + l15;
          const int base = krow * 64 + ((ks * 32 + lk * 8) ^ ((krow & 7) << 3));
          kh[mf] = *(const short8*)&Ks_h[base];
          kl[mf] = *(const short8*)&Ks_l[base];
        }
#pragma unroll
        for (int mf = 0; mf < 4; ++mf)
#pragma unroll
          for (int nf = 0; nf < 2; ++nf) {
            sacc[mf][nf] = __builtin_amdgcn_mfma_f32_16x16x32_bf16(
                kh[mf], qh[nf][ks], sacc[mf][nf], 0, 0, 0);
            sacc[mf][nf] = __builtin_amdgcn_mfma_f32_16x16x32_bf16(
                kh[mf], ql[nf][ks], sacc[mf][nf], 0, 0, 0);
            sacc[mf][nf] = __builtin_amdgcn_mfma_f32_16x16x32_bf16(
                kl[mf], qh[nf][ks], sacc[mf][nf], 0, 0, 0);
          }
      }

      // online softmax per query column (nf): in-lane 16 keys + lk reduce
      float c[2];
#pragma unroll
      for (int nf = 0; nf < 2; ++nf) {
        float cm = sacc[0][nf][0];
#pragma unroll
        for (int mf = 0; mf < 4; ++mf)
#pragma unroll
          for (int i = 0; i < 4; ++i) cm = fmaxf(cm, sacc[mf][nf][i]);
        cm = fmaxf(cm, __shfl_xor(cm, 16));
        cm = fmaxf(cm, __shfl_xor(cm, 32));
        const float mn = fmaxf(m[nf], cm);
        c[nf] = __expf(m[nf] - mn);
        m[nf] = mn;
        float ps = 0.f;
        const int qrow = qb + nf * 16 + l15;
        const int qmk = (qrow & 7) << 3;
#pragma unroll
        for (int mf = 0; mf < 4; ++mf) {
          float p0 = __expf(sacc[mf][nf][0] - mn);
          float p1 = __expf(sacc[mf][nf][1] - mn);
          float p2 = __expf(sacc[mf][nf][2] - mn);
          float p3 = __expf(sacc[mf][nf][3] - mn);
          ps += (p0 + p1) + (p2 + p3);
          const ushort h0 = f32_bf16_rne(p0), h1 = f32_bf16_rne(p1);
          const ushort h2 = f32_bf16_rne(p2), h3 = f32_bf16_rne(p3);
          uint2 hw, lw;
          hw.x = (uint32_t)h0 | ((uint32_t)h1 << 16);
          hw.y = (uint32_t)h2 | ((uint32_t)h3 << 16);
          lw.x = (uint32_t)f32_bf16_rne(p0 - bf16_f32(h0)) |
                 ((uint32_t)f32_bf16_rne(p1 - bf16_f32(h1)) << 16);
          lw.y = (uint32_t)f32_bf16_rne(p2 - bf16_f32(h2)) |
                 ((uint32_t)f32_bf16_rne(p3 - bf16_f32(h3)) << 16);
          const int off = qrow * 64 + ((mf * 16 + lk * 4) ^ qmk);
          *(uint2*)&Ps_h[off] = hw;
          *(uint2*)&Ps_l[off] = lw;
        }
        ps += __shfl_xor(ps, 16);
        ps += __shfl_xor(ps, 32);
        lsum[nf] = lsum[nf] * c[nf] + ps;
      }
      // rescale O accumulator
#pragma unroll
      for (int mo = 0; mo < 2; ++mo)
#pragma unroll
        for (int i = 0; i < 4; ++i) {
          const float cq = __shfl(c[mo], lk * 4 + i);
#pragma unroll
          for (int no = 0; no < 4; ++no) accO[mo][no][i] *= cq;
        }

      // PV: O[q][d] += P[q][key] * Vt[d][key]
#pragma unroll
      for (int ks = 0; ks < 2; ++ks) {
        short8 pa_h[2], pa_l[2], vb_h[4], vb_l[4];
#pragma unroll
        for (int mo = 0; mo < 2; ++mo) {
          const int qrow = qb + mo * 16 + l15;
          const int base = qrow * 64 + ((ks * 32 + lk * 8) ^ ((qrow & 7) << 3));
          pa_h[mo] = *(const short8*)&Ps_h[base];
          pa_l[mo] = *(const short8*)&Ps_l[base];
        }
#pragma unroll
        for (int no = 0; no < 4; ++no) {
          const int vrow = no * 16 + l15;
          const int base = vrow * 64 + ((ks * 32 + lk * 8) ^ ((vrow & 7) << 3));
          vb_h[no] = *(const short8*)&Vs_h[base];
          vb_l[no] = *(const short8*)&Vs_l[base];
        }
#pragma unroll
        for (int mo = 0; mo < 2; ++mo)
#pragma unroll
          for (int no = 0; no < 4; ++no) {
            accO[mo][no] = __builtin_amdgcn_mfma_f32_16x16x32_bf16(
                pa_h[mo], vb_h[no], accO[mo][no], 0, 0, 0);
            accO[mo][no] = __builtin_amdgcn_mfma_f32_16x16x32_bf16(
                pa_h[mo], vb_l[no], accO[mo][no], 0, 0, 0);
            accO[mo][no] = __builtin_amdgcn_mfma_f32_16x16x32_bf16(
                pa_l[mo], vb_h[no], accO[mo][no], 0, 0, 0);
          }
      }
    }
  }

  // normalize and write O pre-split h/l in [B,S,DM] layout for GEMM2
  const float il0 = 1.f / lsum[0];
  const float il1 = 1.f / lsum[1];
#pragma unroll
  for (int mo = 0; mo < 2; ++mo) {
    const float myil = (mo == 0) ? il0 : il1;
#pragma unroll
    for (int i = 0; i < 4; ++i) {
      const float wv = __shfl(myil, lk * 4 + i);
      const int srow = f * CTPF + qb + mo * 16 + lk * 4 + i;
      const size_t obase = (size_t)(b * CS + srow) * CDM + h * CHD;
#pragma unroll
      for (int no = 0; no < 4; ++no) {
        const float val = accO[mo][no][i] * wv;
        const ushort hh = f32_bf16_rne(val);
        Oh[obase + no * 16 + l15] = hh;
        Ol[obase + no * 16 + l15] = f32_bf16_rne(val - bf16_f32(hh));
      }
    }
  }
}

// ---------------------------------------------------------------------------
extern "C" void kernel_launch(void* const* d_in, const int* in_sizes, int n_in,
                              void* d_out, int out_size, void* d_ws, size_t ws_size,
                              hipStream_t stream) {
  const float* x       = (const float*)d_in[0];
  const float* Wqkv    = (const float*)d_in[1];
  const float* bqkv    = (const float*)d_in[2];
  const float* q_scale = (const float*)d_in[3];
  const float* k_scale = (const float*)d_in[4];
  const float* Wout    = (const float*)d_in[5];
  const float* bout    = (const float*)d_in[6];
  float* out = (float*)d_out;

  // Workspace layout (ushort units). Temporal aliasing:
  //  region0 (50.3 MB): qkv fp32 [live GEMM1..prep]  ->  Oh/Ol [live attn..GEMM2]
  //  region1 (50.3 MB): xh/xl/Wqh/Wql [live split..GEMM1] -> Qh..Vtl [prep..attn]
  //  region2 ( 4.2 MB): Wouth/Woutl [live split..GEMM2]
  ushort* W = (ushort*)d_ws;
  const size_t qkvN = (size_t)(CB * CS) * (3 * CDM);   // 12.58M floats
  const size_t perA = (size_t)CB * CH * CS * CHD;      // 4.19M elems
  const size_t WqN  = (size_t)(3 * CDM) * CDM;         // 3.15M
  const size_t WoN  = (size_t)CDM * CDM;               // 1.05M

  float*  qkvF = (float*)W;
  ushort* Oh   = W;                    // aliases qkvF (dead after prep)
  ushort* Ol   = W + perA;
  ushort* R1   = W + 2 * qkvN;
  ushort* Qh = R1;            ushort* Ql = R1 + perA;
  ushort* Kh = R1 + 2 * perA; ushort* Kl = R1 + 3 * perA;
  ushort* Vth = R1 + 4 * perA; ushort* Vtl = R1 + 5 * perA;
  ushort* xh  = R1;            ushort* xl  = R1 + perA;   // alias Qh/Ql
  ushort* Wqh = R1 + 2 * perA; ushort* Wql = Wqh + WqN;   // alias Kh..
  ushort* Wouth = R1 + 6 * perA; ushort* Woutl = Wouth + WoN;

  // 0) one-time fp32 -> bf16 h/l splits (memory-bound)
  split_pass<<<2048, 256, 0, stream>>>(x, xh, xl, (int)(perA / 8));
  split_pass<<<1536, 256, 0, stream>>>(Wqkv, Wqh, Wql, (int)(WqN / 8));
  split_pass<<<512, 256, 0, stream>>>(Wout, Wouth, Woutl, (int)(WoN / 8));

  // 1) qkv = x @ Wqkv^T + bqkv
  dim3 g1((3 * CDM) / 128, (CB * CS) / 128);
  gemm_ps<<<g1, 256, 0, stream>>>(xh, xl, Wqh, Wql, bqkv, qkvF,
                                  CB * CS, 3 * CDM, CDM);

  // 2) RMSNorm + RoPE; pre-split Q (scaled), K, Vt to bf16 h/l
  dim3 g2(CS / 64, CH, CB);
  qkv_prep<<<g2, 256, 0, stream>>>(qkvF, q_scale, k_scale,
                                   Qh, Ql, Kh, Kl, Vth, Vtl);

  // 3) frame-block-causal attention on MFMA -> pre-split O
  //    grid (batch, head, fsel): balanced complementary frame pairs per CU
  dim3 g3(CB, CH, CNF);
  attn_fwd_mfma<<<g3, 256, 0, stream>>>(Qh, Ql, Kh, Kl, Vth, Vtl, Oh, Ol);

  // 4) out = O @ Wout^T + bout
  dim3 g4(CDM / 128, (CB * CS) / 128);
  gemm_ps<<<g4, 256, 0, stream>>>(Oh, Ol, Wouth, Woutl, bout, out,
                                  CB * CS, CDM, CDM);
}